// Round 4
// baseline (265.977 us; speedup 1.0000x reference)
//
#include <hip/hip_runtime.h>
#include <hip/hip_bf16.h>
#include <stdint.h>
#include <math.h>

#define DI __device__ __forceinline__

typedef unsigned short u16;
typedef __bf16   bf16x8 __attribute__((ext_vector_type(8)));
typedef float    f32x4  __attribute__((ext_vector_type(4)));

// Problem constants
#define BSZ 4
#define SEQ 2048
#define DMODEL 1024
#define NHEAD 16
#define DHEAD 64

DI u16 f2b(float f) {            // fp32 -> bf16 bits, round-to-nearest-even
    uint32_t u = __float_as_uint(f);
    u += 0x7fffu + ((u >> 16) & 1u);
    return (u16)(u >> 16);
}

DI uint32_t f2b2(float a, float b) {   // packed cvt (v_cvt_pk_bf16_f32 on gfx950)
    __hip_bfloat162 h = __float22bfloat162_rn(float2{a, b});
    uint32_t u; __builtin_memcpy(&u, &h, 4); return u;
}

DI void async16(const void* g, void* l) {
    __builtin_amdgcn_global_load_lds(
        (const __attribute__((address_space(1))) void*)g,
        (__attribute__((address_space(3))) void*)l, 16, 0, 0);
}

// ---------------- fused cast + out-bias-init kernel -------------------------
// region 0: x 2097152 f4 | region 1: wq 786432 | region 2: wf 262144
// region 3: out init with bias: 2097152 f4   -> total 5242880 = 20480 * 256
__global__ __launch_bounds__(256) void cast_all(
    const float* __restrict__ x,  const float* __restrict__ wq,
    const float* __restrict__ wf, const float* __restrict__ bias,
    u16* __restrict__ xb, u16* __restrict__ wqb, u16* __restrict__ wfb,
    float* __restrict__ outF)
{
    const int idx = blockIdx.x * 256 + threadIdx.x;
    if (idx >= 3145728) {                  // out init: out[m][e] = bias[e]
        const int off = idx - 3145728;     // 0..2097151 ; 256 f4 per row
        *(f32x4*)(outF + off * 4) = *(const f32x4*)(bias + (off & 255) * 4);
        return;
    }
    const float* src; u16* dst; int off;
    if (idx < 2097152)      { src = x;  dst = xb;  off = idx; }
    else if (idx < 2883584) { src = wq; dst = wqb; off = idx - 2097152; }
    else                    { src = wf; dst = wfb; off = idx - 2883584; }
    const int i = off * 4;
    f32x4 v = *(const f32x4*)(src + i);
    *(uint2*)(dst + i) = make_uint2(f2b2(v[0], v[1]), f2b2(v[2], v[3]));
}

// ---------------- GEMM: C[M,N] = A[M,K] * B[N,K]^T  (bf16 in, fp32 acc) -----
// BK=64 (128-B LDS rows) with XOR chunk swizzle (global source chunk c^=row&7;
// fragment reads de-swizzle -> 2 lanes/bank, conflict-free).
// MODE 0: epilogue scatters bf16 into q/k/v buffers laid out [B,H,S,64]
// MODE 1: split-K over blockIdx.z (KS chunks of K); epilogue atomicAdd fp32
//         into outF (pre-initialized with bias by cast_all).
template <int MODE, int KS>
__global__ __launch_bounds__(256) void gemm_bt(
    const u16* __restrict__ A, const u16* __restrict__ Bm, int K,
    u16* __restrict__ qb, u16* __restrict__ kb, u16* __restrict__ vb,
    float* __restrict__ outF, int N)
{
    __shared__ u16 As[128 * 64];   // row-major [128][64], chunk-swizzled
    __shared__ u16 Bs[128 * 64];

    const int tid  = threadIdx.x;
    const int l    = tid & 63, w = tid >> 6;
    const int quad = l >> 4, lc = l & 15;
    const int wm   = w >> 1, wn = w & 1;
    const int m0   = blockIdx.y * 128, n0 = blockIdx.x * 128;
    const int kb0  = (MODE == 1) ? blockIdx.z * KS : 0;
    const int kb1  = (MODE == 1) ? kb0 + KS : K;

    f32x4 acc[4][4];
#pragma unroll
    for (int i = 0; i < 4; i++)
#pragma unroll
        for (int j = 0; j < 4; j++) acc[i][j] = (f32x4){0.f, 0.f, 0.f, 0.f};

    const int  srow   = tid >> 3;
    const int  schunk = (tid & 7) ^ (srow & 7);
    const size_t aBase = (size_t)(m0 + srow) * K + schunk * 8;
    const size_t bBase = (size_t)(n0 + srow) * K + schunk * 8;

    for (int k0 = kb0; k0 < kb1; k0 += 64) {
        __syncthreads();
#pragma unroll
        for (int i = 0; i < 4; i++) {
            async16(A  + aBase + (size_t)(32 * i) * K + k0, As + i * 2048 + w * 512);
            async16(Bm + bBase + (size_t)(32 * i) * K + k0, Bs + i * 2048 + w * 512);
        }
        __syncthreads();

#pragma unroll
        for (int kh = 0; kh < 2; kh++) {
            bf16x8 af[4], bf[4];
            const int g = kh * 4 + quad;
#pragma unroll
            for (int mi = 0; mi < 4; mi++) {
                const int mr = wm * 64 + mi * 16 + lc;
                af[mi] = *(const bf16x8*)&As[mr * 64 + ((g ^ (mr & 7)) * 8)];
            }
#pragma unroll
            for (int ni = 0; ni < 4; ni++) {
                const int nr = wn * 64 + ni * 16 + lc;
                bf[ni] = *(const bf16x8*)&Bs[nr * 64 + ((g ^ (nr & 7)) * 8)];
            }
#pragma unroll
            for (int mi = 0; mi < 4; mi++)
#pragma unroll
                for (int ni = 0; ni < 4; ni++)
                    acc[mi][ni] = __builtin_amdgcn_mfma_f32_16x16x32_bf16(
                        af[mi], bf[ni], acc[mi][ni], 0, 0, 0);
        }
    }

    // epilogue: C row = m0+wm*64+mi*16+quad*4+r ; col = n0+wn*64+ni*16+lc
#pragma unroll
    for (int mi = 0; mi < 4; mi++) {
        const int mrow = m0 + wm * 64 + mi * 16 + quad * 4;
#pragma unroll
        for (int ni = 0; ni < 4; ni++) {
            const int e = n0 + wn * 64 + ni * 16 + lc;
#pragma unroll
            for (int r = 0; r < 4; r++) {
                const int m = mrow + r;
                const float v = acc[mi][ni][r];
                if (MODE == 0) {
                    const int part = e >> 10, rem = e & 1023;
                    const int h = rem >> 6, dh = rem & 63;
                    const int b = m >> 11, s = m & 2047;
                    u16* dst = (part == 0) ? qb : ((part == 1) ? kb : vb);
                    dst[(((size_t)(b * NHEAD + h) * SEQ + s) << 6) + dh] = f2b(v);
                } else {
                    atomicAdd(&outF[(size_t)m * N + e], v);
                }
            }
        }
    }
}

// ---------------- fused attention (flash-style, static-max softmax) ---------
// grid: (S/64, H, B); block 256 = 4 waves; wave w owns 16 q-rows (1 m-tile).
// 64-row q-blocks: 4 blocks/CU (LDS 26.6 KB) and a tighter Gaussian window.
// Gaussian window: keys at distance d carry weight <= exp(gap - shift*d^2);
// cutoff shift*d^2 > 30 -> skipped mass < ~4e-6 (bf16 floor is ~0.03).
// Static-max softmax: p = exp(s - 8) exact in fp32 (scores bounded ~|s|<10).
#define PST 72   // Ps/Vt LDS row stride (u16): mult of 8 for b128, non-pow2 banks
__global__ __launch_bounds__(256) void attn_kernel(
    const u16* __restrict__ Q, const u16* __restrict__ Kg, const u16* __restrict__ Vg,
    const int* __restrict__ mask, const int* __restrict__ gaussp,
    const float* __restrict__ shiftp, const float* __restrict__ biaspp,
    u16* __restrict__ outA)
{
    __shared__ u16 Ks[8 * 64 * 8];     // [cb 0..7][row 0..63][8] (global_load_lds layout)
    __shared__ u16 Vt[64 * PST];       // transposed V: Vt[dh][k]
    __shared__ u16 Ps[64 * PST];       // P tiles, row = w*16 + local row (A-layout)

    const int tid  = threadIdx.x;
    const int l    = tid & 63, w = tid >> 6;
    const int quad = l >> 4, lc = l & 15;
    const int qt = blockIdx.x, h = blockIdx.y, b = blockIdx.z;
    const int bh = b * NHEAD + h;
    const int q0 = qt * 64;

    const float shift = shiftp[0];
    const float biasp = biaspp[0];
    const int   gauss = gaussp[0];

    const u16* Qbase = Q  + ((size_t)bh * SEQ << 6);
    const u16* Kbase = Kg + ((size_t)bh * SEQ << 6);
    const u16* Vbase = Vg + ((size_t)bh * SEQ << 6);
    const int* mbase = mask + b * SEQ;

    // Gaussian locality window (block-uniform)
    int kt_lo = 0, kt_hi = SEQ / 64 - 1;
    if (gauss) {
        const int dwin = (int)__fsqrt_rn(30.0f / shift) + 1;
        int lo = q0 - dwin;          if (lo < 0) lo = 0;
        int hi = q0 + 63 + dwin;     if (hi > SEQ - 1) hi = SEQ - 1;
        kt_lo = lo >> 6;
        kt_hi = hi >> 6;
    }

    // Q fragment: wave w rows q0 + w*16 + lc, d = ks*32 + quad*8
    bf16x8 qf[2];
#pragma unroll
    for (int ks = 0; ks < 2; ks++)
        qf[ks] = *(const bf16x8*)(Qbase +
            ((size_t)(q0 + w * 16 + lc) << 6) + ks * 32 + quad * 8);

    f32x4 oacc[4];
#pragma unroll
    for (int dt = 0; dt < 4; dt++) oacc[dt] = (f32x4){0.f, 0.f, 0.f, 0.f};
    float lsum[4];
#pragma unroll
    for (int r = 0; r < 4; r++) lsum[r] = 0.f;

    for (int kt = kt_lo; kt <= kt_hi; ++kt) {
        const int kk0 = kt * 64;
        __syncthreads();   // protect Ks/Vt reuse

        // stage K tile: issue0 cb=w, issue1 cb=4+w ; row = lane
        async16(Kbase + (size_t)(kk0 + l) * 64 + w * 8,       Ks + w * 512);
        async16(Kbase + (size_t)(kk0 + l) * 64 + (4 + w) * 8, Ks + 2048 + w * 512);

        // stage V transposed: wave w -> dh rows [w*16, w*16+16), lane = key index
        {
            const u16* vg = Vbase + (size_t)(kk0 + l) * 64 + w * 16;
            bf16x8 v0 = *(const bf16x8*)vg;
            bf16x8 v1 = *(const bf16x8*)(vg + 8);
            const u16* v0b = (const u16*)&v0;
            const u16* v1b = (const u16*)&v1;
#pragma unroll
            for (int j = 0; j < 8; j++) Vt[(w * 16 + j) * PST + l] = v0b[j];
#pragma unroll
            for (int j = 0; j < 8; j++) Vt[(w * 16 + 8 + j) * PST + l] = v1b[j];
        }
        __syncthreads();   // staging + transpose visible

        // ---- QK^T : S[q 16][kk 64] per wave ----
        bf16x8 kf[4][2];
#pragma unroll
        for (int nt = 0; nt < 4; nt++)
#pragma unroll
            for (int ks = 0; ks < 2; ks++)
                kf[nt][ks] = *(const bf16x8*)&Ks[(ks * 4 + quad) * 512 + (nt * 16 + lc) * 8];

        f32x4 sf[4];
#pragma unroll
        for (int nt = 0; nt < 4; nt++) sf[nt] = (f32x4){0.f, 0.f, 0.f, 0.f};
#pragma unroll
        for (int nt = 0; nt < 4; nt++)
#pragma unroll
            for (int ks = 0; ks < 2; ks++)
                sf[nt] = __builtin_amdgcn_mfma_f32_16x16x32_bf16(
                    qf[ks], kf[nt][ks], sf[nt], 0, 0, 0);

        // ---- mask + Gaussian + static-max softmax ----
        float madd[4]; float jj[4];
#pragma unroll
        for (int nt = 0; nt < 4; nt++) {
            const int j = kk0 + nt * 16 + lc;
            madd[nt] = mbase[j] ? 0.f : -1e30f;
            jj[nt] = (float)j;
        }
#pragma unroll
        for (int r = 0; r < 4; r++) {
            const float fi = (float)(q0 + w * 16 + quad * 4 + r);
            float p[4];
#pragma unroll
            for (int nt = 0; nt < 4; nt++) {
                float s = sf[nt][r] * 0.125f + madd[nt] - 8.0f;
                if (gauss) { const float d = fi - jj[nt]; s -= shift * d * d + biasp; }
                p[nt] = __expf(s);
            }
            lsum[r] += (p[0] + p[1]) + (p[2] + p[3]);
            const uint32_t p01 = f2b2(p[0], p[1]);
            const uint32_t p23 = f2b2(p[2], p[3]);
            u16* prow = &Ps[(w * 16 + quad * 4 + r) * PST + lc];
            prow[0]  = (u16)p01;  prow[16] = (u16)(p01 >> 16);
            prow[32] = (u16)p23;  prow[48] = (u16)(p23 >> 16);
        }

        // ---- P·V ----
        bf16x8 pa[2], vf[4][2];
#pragma unroll
        for (int ks = 0; ks < 2; ks++)
            pa[ks] = *(const bf16x8*)&Ps[(w * 16 + lc) * PST + ks * 32 + quad * 8];
#pragma unroll
        for (int dt = 0; dt < 4; dt++)
#pragma unroll
            for (int ks = 0; ks < 2; ks++)
                vf[dt][ks] = *(const bf16x8*)&Vt[(dt * 16 + lc) * PST + ks * 32 + quad * 8];
#pragma unroll
        for (int dt = 0; dt < 4; dt++)
#pragma unroll
            for (int ks = 0; ks < 2; ks++)
                oacc[dt] = __builtin_amdgcn_mfma_f32_16x16x32_bf16(
                    pa[ks], vf[dt][ks], oacc[dt], 0, 0, 0);
    }

    // row sums: reduce lsum across the 16 lc lanes (stays within quad group)
    float lrow[4];
#pragma unroll
    for (int r = 0; r < 4; r++) {
        float ts = lsum[r];
        ts += __shfl_xor(ts, 1);
        ts += __shfl_xor(ts, 2);
        ts += __shfl_xor(ts, 4);
        ts += __shfl_xor(ts, 8);
        lrow[r] = ts;
    }

    // epilogue: out[b, q, h*64+dh] = O / l   (bf16)
#pragma unroll
    for (int dt = 0; dt < 4; dt++)
#pragma unroll
        for (int r = 0; r < 4; r++) {
            const int qg  = q0 + w * 16 + quad * 4 + r;
            const int col = h * 64 + dt * 16 + lc;
            const float v = oacc[dt][r] / lrow[r];
            outA[((size_t)(b * SEQ + qg) << 10) + col] = f2b(v);
        }
}

// ---------------------------------------------------------------------------
extern "C" void kernel_launch(void* const* d_in, const int* in_sizes, int n_in,
                              void* d_out, int out_size, void* d_ws, size_t ws_size,
                              hipStream_t stream)
{
    const float* x      = (const float*)d_in[0];
    const int*   mask   = (const int*)d_in[1];
    // d_in[2] = qmask (unused by reference)
    const int*   gaussp = (const int*)d_in[3];
    const float* w_qkv  = (const float*)d_in[4];
    const float* w_fc   = (const float*)d_in[5];
    const float* b_fc   = (const float*)d_in[6];
    const float* shiftp = (const float*)d_in[7];
    const float* biaspp = (const float*)d_in[8];
    float* out = (float*)d_out;

    char* ws = (char*)d_ws;
    u16* xb  = (u16*)(ws);               // x bf16, later reused as attn_out (16.78 MB)
    u16* wqb = (u16*)(ws + 16777216);    // w_qkv bf16 (6.29 MB)
    u16* wfb = (u16*)(ws + 23068672);    // w_fc bf16 (2.10 MB)
    u16* qb  = (u16*)(ws + 25165824);    // Q bf16 [B,H,S,64] (16.78 MB)
    u16* kb  = (u16*)(ws + 41943040);    // K bf16 (16.78 MB)
    u16* vb  = (u16*)(ws + 58720256);    // V bf16 (16.78 MB) -> total 75.5 MB

    // casts + out := bias (enables split-K atomic accumulation)
    cast_all<<<20480, 256, 0, stream>>>(x, w_qkv, w_fc, b_fc, xb, wqb, wfb, out);

    // QKV projection: M=8192, N=3072, K=1024
    gemm_bt<0, 1024><<<dim3(24, 64), 256, 0, stream>>>(
        xb, wqb, DMODEL, qb, kb, vb, nullptr, 3 * DMODEL);

    // fused attention -> attn_out (reuses xb)
    attn_kernel<<<dim3(SEQ / 64, NHEAD, BSZ), 256, 0, stream>>>(
        qb, kb, vb, mask, gaussp, shiftp, biaspp, xb);

    // output projection: M=8192, N=1024, K=1024 split-K x2, atomic into out
    gemm_bt<1, 512><<<dim3(8, 64, 2), 256, 0, stream>>>(
        xb, wfb, DMODEL, nullptr, nullptr, nullptr, out, DMODEL);
}

// Round 5
// 219.114 us; speedup vs baseline: 1.2139x; 1.2139x over previous
//
#include <hip/hip_runtime.h>
#include <hip/hip_bf16.h>
#include <stdint.h>
#include <math.h>

#define DI __device__ __forceinline__

typedef unsigned short u16;
typedef __bf16   bf16x8 __attribute__((ext_vector_type(8)));
typedef float    f32x4  __attribute__((ext_vector_type(4)));

// Problem constants
#define BSZ 4
#define SEQ 2048
#define DMODEL 1024
#define NHEAD 16
#define DHEAD 64

DI u16 f2b(float f) {            // fp32 -> bf16 bits, round-to-nearest-even
    uint32_t u = __float_as_uint(f);
    u += 0x7fffu + ((u >> 16) & 1u);
    return (u16)(u >> 16);
}

DI uint32_t f2b2(float a, float b) {   // packed cvt (v_cvt_pk_bf16_f32 on gfx950)
    __hip_bfloat162 h = __float22bfloat162_rn(float2{a, b});
    uint32_t u; __builtin_memcpy(&u, &h, 4); return u;
}

DI void async16(const void* g, void* l) {
    __builtin_amdgcn_global_load_lds(
        (const __attribute__((address_space(1))) void*)g,
        (__attribute__((address_space(3))) void*)l, 16, 0, 0);
}

// ---------------- fused cast kernel: fp32 -> bf16, all three arrays ---------
// x: 2097152 float4s, w_qkv: 786432, w_fc: 262144 -> 3145728 = 12288 * 256
__global__ __launch_bounds__(256) void cast_all(
    const float* __restrict__ x,  const float* __restrict__ wq,
    const float* __restrict__ wf, u16* __restrict__ xb,
    u16* __restrict__ wqb, u16* __restrict__ wfb)
{
    const int idx = blockIdx.x * 256 + threadIdx.x;
    const float* src; u16* dst; int off;
    if (idx < 2097152)      { src = x;  dst = xb;  off = idx; }
    else if (idx < 2883584) { src = wq; dst = wqb; off = idx - 2097152; }
    else                    { src = wf; dst = wfb; off = idx - 2883584; }
    const int i = off * 4;
    f32x4 v = *(const f32x4*)(src + i);
    *(uint2*)(dst + i) = make_uint2(f2b2(v[0], v[1]), f2b2(v[2], v[3]));
}

// ---------------- QKV GEMM (control: identical to R3) -----------------------
// C[M,N] = A[M,K] * B[N,K]^T, BK=64, XOR chunk swizzle (0 bank conflicts),
// epilogue scatters bf16 into q/k/v buffers laid out [B,H,S,64].
__global__ __launch_bounds__(256) void gemm_qkv(
    const u16* __restrict__ A, const u16* __restrict__ Bm, int K,
    u16* __restrict__ qb, u16* __restrict__ kb, u16* __restrict__ vb)
{
    __shared__ u16 As[128 * 64];
    __shared__ u16 Bs[128 * 64];

    const int tid  = threadIdx.x;
    const int l    = tid & 63, w = tid >> 6;
    const int quad = l >> 4, lc = l & 15;
    const int wm   = w >> 1, wn = w & 1;
    const int m0   = blockIdx.y * 128, n0 = blockIdx.x * 128;

    f32x4 acc[4][4];
#pragma unroll
    for (int i = 0; i < 4; i++)
#pragma unroll
        for (int j = 0; j < 4; j++) acc[i][j] = (f32x4){0.f, 0.f, 0.f, 0.f};

    const int  srow   = tid >> 3;
    const int  schunk = (tid & 7) ^ (srow & 7);
    const size_t aBase = (size_t)(m0 + srow) * K + schunk * 8;
    const size_t bBase = (size_t)(n0 + srow) * K + schunk * 8;

    for (int k0 = 0; k0 < K; k0 += 64) {
        __syncthreads();
#pragma unroll
        for (int i = 0; i < 4; i++) {
            async16(A  + aBase + (size_t)(32 * i) * K + k0, As + i * 2048 + w * 512);
            async16(Bm + bBase + (size_t)(32 * i) * K + k0, Bs + i * 2048 + w * 512);
        }
        __syncthreads();

#pragma unroll
        for (int kh = 0; kh < 2; kh++) {
            bf16x8 af[4], bf[4];
            const int g = kh * 4 + quad;
#pragma unroll
            for (int mi = 0; mi < 4; mi++) {
                const int mr = wm * 64 + mi * 16 + lc;
                af[mi] = *(const bf16x8*)&As[mr * 64 + ((g ^ (mr & 7)) * 8)];
            }
#pragma unroll
            for (int ni = 0; ni < 4; ni++) {
                const int nr = wn * 64 + ni * 16 + lc;
                bf[ni] = *(const bf16x8*)&Bs[nr * 64 + ((g ^ (nr & 7)) * 8)];
            }
#pragma unroll
            for (int mi = 0; mi < 4; mi++)
#pragma unroll
                for (int ni = 0; ni < 4; ni++)
                    acc[mi][ni] = __builtin_amdgcn_mfma_f32_16x16x32_bf16(
                        af[mi], bf[ni], acc[mi][ni], 0, 0, 0);
        }
    }

#pragma unroll
    for (int mi = 0; mi < 4; mi++) {
        const int mrow = m0 + wm * 64 + mi * 16 + quad * 4;
#pragma unroll
        for (int ni = 0; ni < 4; ni++) {
            const int e = n0 + wn * 64 + ni * 16 + lc;
#pragma unroll
            for (int r = 0; r < 4; r++) {
                const int m = mrow + r;
                const int part = e >> 10, rem = e & 1023;
                const int h = rem >> 6, dh = rem & 63;
                const int b = m >> 11, s = m & 2047;
                u16* dst = (part == 0) ? qb : ((part == 1) ? kb : vb);
                dst[(((size_t)(b * NHEAD + h) * SEQ + s) << 6) + dh] = f2b(acc[mi][ni][r]);
            }
        }
    }
}

// ---------------- out-proj GEMM: double-buffered LDS ------------------------
// Grid is 512 blocks = exactly 2/CU -> no other blocks mask the per-tile
// barrier drain. Fix: 2-deep LDS double buffer (64 KB, still 2 blocks/CU):
// prefetch tile k+1 into the other buffer before computing tile k, so the
// global->LDS DMA has the whole compute phase to land. Epilogue: + bias,
// fp32 direct store (atomics reverted — R4 post-mortem).
__global__ __launch_bounds__(256) void gemm_fc(
    const u16* __restrict__ A, const u16* __restrict__ Bm, int K,
    const float* __restrict__ bias, float* __restrict__ outF, int N)
{
    __shared__ u16 As[2][128 * 64];
    __shared__ u16 Bs[2][128 * 64];

    const int tid  = threadIdx.x;
    const int l    = tid & 63, w = tid >> 6;
    const int quad = l >> 4, lc = l & 15;
    const int wm   = w >> 1, wn = w & 1;
    const int m0   = blockIdx.y * 128, n0 = blockIdx.x * 128;

    f32x4 acc[4][4];
#pragma unroll
    for (int i = 0; i < 4; i++)
#pragma unroll
        for (int j = 0; j < 4; j++) acc[i][j] = (f32x4){0.f, 0.f, 0.f, 0.f};

    const int  srow   = tid >> 3;
    const int  schunk = (tid & 7) ^ (srow & 7);
    const size_t aBase = (size_t)(m0 + srow) * K + schunk * 8;
    const size_t bBase = (size_t)(n0 + srow) * K + schunk * 8;

    const int NT = K / 64;   // 16 tiles

    // prologue: stage tile 0 into buf 0
#pragma unroll
    for (int i = 0; i < 4; i++) {
        async16(A  + aBase + (size_t)(32 * i) * K, As[0] + i * 2048 + w * 512);
        async16(Bm + bBase + (size_t)(32 * i) * K, Bs[0] + i * 2048 + w * 512);
    }
    __syncthreads();

    for (int kt = 0; kt < NT; ++kt) {
        const int cur = kt & 1;
        if (kt + 1 < NT) {
            const int nxt = (kt + 1) & 1;
            const int k0  = (kt + 1) * 64;
#pragma unroll
            for (int i = 0; i < 4; i++) {
                async16(A  + aBase + (size_t)(32 * i) * K + k0, As[nxt] + i * 2048 + w * 512);
                async16(Bm + bBase + (size_t)(32 * i) * K + k0, Bs[nxt] + i * 2048 + w * 512);
            }
        }

#pragma unroll
        for (int kh = 0; kh < 2; kh++) {
            bf16x8 af[4], bf[4];
            const int g = kh * 4 + quad;
#pragma unroll
            for (int mi = 0; mi < 4; mi++) {
                const int mr = wm * 64 + mi * 16 + lc;
                af[mi] = *(const bf16x8*)&As[cur][mr * 64 + ((g ^ (mr & 7)) * 8)];
            }
#pragma unroll
            for (int ni = 0; ni < 4; ni++) {
                const int nr = wn * 64 + ni * 16 + lc;
                bf[ni] = *(const bf16x8*)&Bs[cur][nr * 64 + ((g ^ (nr & 7)) * 8)];
            }
#pragma unroll
            for (int mi = 0; mi < 4; mi++)
#pragma unroll
                for (int ni = 0; ni < 4; ni++)
                    acc[mi][ni] = __builtin_amdgcn_mfma_f32_16x16x32_bf16(
                        af[mi], bf[ni], acc[mi][ni], 0, 0, 0);
        }
        __syncthreads();   // drains prefetch; next iter consumes it
    }

#pragma unroll
    for (int mi = 0; mi < 4; mi++) {
        const int mrow = m0 + wm * 64 + mi * 16 + quad * 4;
#pragma unroll
        for (int ni = 0; ni < 4; ni++) {
            const int e = n0 + wn * 64 + ni * 16 + lc;
            const float be = bias[e];
#pragma unroll
            for (int r = 0; r < 4; r++)
                outF[(size_t)(mrow + r) * N + e] = acc[mi][ni][r] + be;
        }
    }
}

// ---------------- fused attention (flash-style, static-max softmax) ---------
// grid: (S/64, H, B); block 256 = 4 waves; wave w owns 16 q-rows (1 m-tile).
// 64-row q-blocks: 4+ blocks/CU (LDS 26.6 KB) and a tighter Gaussian window.
// Gaussian window: keys at distance d carry weight <= exp(gap - shift*d^2);
// cutoff shift*d^2 > 30 -> skipped mass < ~4e-6 (bf16 floor is ~0.03).
// Static-max softmax: p = exp(s - 8) exact in fp32 (scores bounded ~|s|<10).
#define PST 72   // Ps/Vt LDS row stride (u16): mult of 8 for b128, non-pow2 banks
__global__ __launch_bounds__(256) void attn_kernel(
    const u16* __restrict__ Q, const u16* __restrict__ Kg, const u16* __restrict__ Vg,
    const int* __restrict__ mask, const int* __restrict__ gaussp,
    const float* __restrict__ shiftp, const float* __restrict__ biaspp,
    u16* __restrict__ outA)
{
    __shared__ u16 Ks[8 * 64 * 8];     // [cb 0..7][row 0..63][8] (global_load_lds layout)
    __shared__ u16 Vt[64 * PST];       // transposed V: Vt[dh][k]
    __shared__ u16 Ps[64 * PST];       // P tiles, row = w*16 + local row (A-layout)

    const int tid  = threadIdx.x;
    const int l    = tid & 63, w = tid >> 6;
    const int quad = l >> 4, lc = l & 15;
    const int qt = blockIdx.x, h = blockIdx.y, b = blockIdx.z;
    const int bh = b * NHEAD + h;
    const int q0 = qt * 64;

    const float shift = shiftp[0];
    const float biasp = biaspp[0];
    const int   gauss = gaussp[0];

    const u16* Qbase = Q  + ((size_t)bh * SEQ << 6);
    const u16* Kbase = Kg + ((size_t)bh * SEQ << 6);
    const u16* Vbase = Vg + ((size_t)bh * SEQ << 6);
    const int* mbase = mask + b * SEQ;

    // Gaussian locality window (block-uniform)
    int kt_lo = 0, kt_hi = SEQ / 64 - 1;
    if (gauss) {
        const int dwin = (int)__fsqrt_rn(30.0f / shift) + 1;
        int lo = q0 - dwin;          if (lo < 0) lo = 0;
        int hi = q0 + 63 + dwin;     if (hi > SEQ - 1) hi = SEQ - 1;
        kt_lo = lo >> 6;
        kt_hi = hi >> 6;
    }

    // Q fragment: wave w rows q0 + w*16 + lc, d = ks*32 + quad*8
    bf16x8 qf[2];
#pragma unroll
    for (int ks = 0; ks < 2; ks++)
        qf[ks] = *(const bf16x8*)(Qbase +
            ((size_t)(q0 + w * 16 + lc) << 6) + ks * 32 + quad * 8);

    f32x4 oacc[4];
#pragma unroll
    for (int dt = 0; dt < 4; dt++) oacc[dt] = (f32x4){0.f, 0.f, 0.f, 0.f};
    float lsum[4];
#pragma unroll
    for (int r = 0; r < 4; r++) lsum[r] = 0.f;

    for (int kt = kt_lo; kt <= kt_hi; ++kt) {
        const int kk0 = kt * 64;
        __syncthreads();   // protect Ks/Vt reuse

        // stage K tile: issue0 cb=w, issue1 cb=4+w ; row = lane
        async16(Kbase + (size_t)(kk0 + l) * 64 + w * 8,       Ks + w * 512);
        async16(Kbase + (size_t)(kk0 + l) * 64 + (4 + w) * 8, Ks + 2048 + w * 512);

        // stage V transposed: wave w -> dh rows [w*16, w*16+16), lane = key index
        {
            const u16* vg = Vbase + (size_t)(kk0 + l) * 64 + w * 16;
            bf16x8 v0 = *(const bf16x8*)vg;
            bf16x8 v1 = *(const bf16x8*)(vg + 8);
            const u16* v0b = (const u16*)&v0;
            const u16* v1b = (const u16*)&v1;
#pragma unroll
            for (int j = 0; j < 8; j++) Vt[(w * 16 + j) * PST + l] = v0b[j];
#pragma unroll
            for (int j = 0; j < 8; j++) Vt[(w * 16 + 8 + j) * PST + l] = v1b[j];
        }
        __syncthreads();   // staging + transpose visible

        // ---- QK^T : S[q 16][kk 64] per wave ----
        bf16x8 kf[4][2];
#pragma unroll
        for (int nt = 0; nt < 4; nt++)
#pragma unroll
            for (int ks = 0; ks < 2; ks++)
                kf[nt][ks] = *(const bf16x8*)&Ks[(ks * 4 + quad) * 512 + (nt * 16 + lc) * 8];

        f32x4 sf[4];
#pragma unroll
        for (int nt = 0; nt < 4; nt++) sf[nt] = (f32x4){0.f, 0.f, 0.f, 0.f};
#pragma unroll
        for (int nt = 0; nt < 4; nt++)
#pragma unroll
            for (int ks = 0; ks < 2; ks++)
                sf[nt] = __builtin_amdgcn_mfma_f32_16x16x32_bf16(
                    qf[ks], kf[nt][ks], sf[nt], 0, 0, 0);

        // ---- mask + Gaussian + static-max softmax ----
        float madd[4]; float jj[4];
#pragma unroll
        for (int nt = 0; nt < 4; nt++) {
            const int j = kk0 + nt * 16 + lc;
            madd[nt] = mbase[j] ? 0.f : -1e30f;
            jj[nt] = (float)j;
        }
#pragma unroll
        for (int r = 0; r < 4; r++) {
            const float fi = (float)(q0 + w * 16 + quad * 4 + r);
            float p[4];
#pragma unroll
            for (int nt = 0; nt < 4; nt++) {
                float s = sf[nt][r] * 0.125f + madd[nt] - 8.0f;
                if (gauss) { const float d = fi - jj[nt]; s -= shift * d * d + biasp; }
                p[nt] = __expf(s);
            }
            lsum[r] += (p[0] + p[1]) + (p[2] + p[3]);
            const uint32_t p01 = f2b2(p[0], p[1]);
            const uint32_t p23 = f2b2(p[2], p[3]);
            u16* prow = &Ps[(w * 16 + quad * 4 + r) * PST + lc];
            prow[0]  = (u16)p01;  prow[16] = (u16)(p01 >> 16);
            prow[32] = (u16)p23;  prow[48] = (u16)(p23 >> 16);
        }

        // ---- P·V ----
        bf16x8 pa[2], vf[4][2];
#pragma unroll
        for (int ks = 0; ks < 2; ks++)
            pa[ks] = *(const bf16x8*)&Ps[(w * 16 + lc) * PST + ks * 32 + quad * 8];
#pragma unroll
        for (int dt = 0; dt < 4; dt++)
#pragma unroll
            for (int ks = 0; ks < 2; ks++)
                vf[dt][ks] = *(const bf16x8*)&Vt[(dt * 16 + lc) * PST + ks * 32 + quad * 8];
#pragma unroll
        for (int dt = 0; dt < 4; dt++)
#pragma unroll
            for (int ks = 0; ks < 2; ks++)
                oacc[dt] = __builtin_amdgcn_mfma_f32_16x16x32_bf16(
                    pa[ks], vf[dt][ks], oacc[dt], 0, 0, 0);
    }

    // row sums: reduce lsum across the 16 lc lanes (stays within quad group)
    float lrow[4];
#pragma unroll
    for (int r = 0; r < 4; r++) {
        float ts = lsum[r];
        ts += __shfl_xor(ts, 1);
        ts += __shfl_xor(ts, 2);
        ts += __shfl_xor(ts, 4);
        ts += __shfl_xor(ts, 8);
        lrow[r] = ts;
    }

    // epilogue: out[b, q, h*64+dh] = O / l   (bf16)
#pragma unroll
    for (int dt = 0; dt < 4; dt++)
#pragma unroll
        for (int r = 0; r < 4; r++) {
            const int qg  = q0 + w * 16 + quad * 4 + r;
            const int col = h * 64 + dt * 16 + lc;
            const float v = oacc[dt][r] / lrow[r];
            outA[((size_t)(b * SEQ + qg) << 10) + col] = f2b(v);
        }
}

// ---------------------------------------------------------------------------
extern "C" void kernel_launch(void* const* d_in, const int* in_sizes, int n_in,
                              void* d_out, int out_size, void* d_ws, size_t ws_size,
                              hipStream_t stream)
{
    const float* x      = (const float*)d_in[0];
    const int*   mask   = (const int*)d_in[1];
    // d_in[2] = qmask (unused by reference)
    const int*   gaussp = (const int*)d_in[3];
    const float* w_qkv  = (const float*)d_in[4];
    const float* w_fc   = (const float*)d_in[5];
    const float* b_fc   = (const float*)d_in[6];
    const float* shiftp = (const float*)d_in[7];
    const float* biaspp = (const float*)d_in[8];
    float* out = (float*)d_out;

    char* ws = (char*)d_ws;
    u16* xb  = (u16*)(ws);               // x bf16, later reused as attn_out (16.78 MB)
    u16* wqb = (u16*)(ws + 16777216);    // w_qkv bf16 (6.29 MB)
    u16* wfb = (u16*)(ws + 23068672);    // w_fc bf16 (2.10 MB)
    u16* qb  = (u16*)(ws + 25165824);    // Q bf16 [B,H,S,64] (16.78 MB)
    u16* kb  = (u16*)(ws + 41943040);    // K bf16 (16.78 MB)
    u16* vb  = (u16*)(ws + 58720256);    // V bf16 (16.78 MB) -> total 75.5 MB

    cast_all<<<12288, 256, 0, stream>>>(x, w_qkv, w_fc, xb, wqb, wfb);

    // QKV projection: M=8192, N=3072, K=1024
    gemm_qkv<<<dim3(24, 64), 256, 0, stream>>>(xb, wqb, DMODEL, qb, kb, vb);

    // fused attention -> attn_out (reuses xb)
    attn_kernel<<<dim3(SEQ / 64, NHEAD, BSZ), 256, 0, stream>>>(
        qb, kb, vb, mask, gaussp, shiftp, biaspp, xb);

    // output projection: M=8192, N=1024, K=1024, dbuf, + bias, fp32 out
    gemm_fc<<<dim3(8, 64), 256, 0, stream>>>(xb, wfb, DMODEL, b_fc, out, DMODEL);
}